// Round 8
// baseline (329.233 us; speedup 1.0000x reference)
//
#include <hip/hip_runtime.h>
#include <hip/hip_bf16.h>

// B=8 S=256 H=768 D=128 L=64, all inputs f32.
// Outputs: relate_score (8*64) | lm_b (8*64*128) | lc_b (8*64*128*128), f32.

#define PITCH 132

typedef __attribute__((ext_vector_type(8))) short bf16x8;
typedef __attribute__((ext_vector_type(4))) float f32x4;

__device__ __forceinline__ float bf2f(unsigned int u) {
    union { unsigned int i; float f; } c; c.i = u << 16; return c.f;
}
__device__ __forceinline__ unsigned short f2bf(float f) {
    __hip_bfloat16 h = __float2bfloat16(f);
    union { __hip_bfloat16 h; unsigned short u; } c; c.h = h; return c.u;
}

// ---------------------------------------------------------------- K1: wm/wv GEMM (+ bf16 wv^T) + sm/sv (blockIdx.x==128)
__global__ __launch_bounds__(256, 2)
void k1_gemm(const float* __restrict__ Am, const float* __restrict__ Av,
             const float* __restrict__ sfm, const float* __restrict__ sfd,
             const float* __restrict__ W1, const float* __restrict__ B1,
             const float* __restrict__ W2, const float* __restrict__ B2,
             const float* __restrict__ W3, const float* __restrict__ B3,
             const float* __restrict__ W4, const float* __restrict__ B4,
             float* __restrict__ wm, float* __restrict__ wv,
             float* __restrict__ sm, float* __restrict__ sv,
             unsigned short* __restrict__ wvTg) {
    __shared__ float At[16][64];
    __shared__ __align__(16) float Wt[64][128];
    __shared__ float tileT[16][129];
    const int tid = threadIdx.x;
    const int sel = blockIdx.y;
    const bool sentB = (blockIdx.x == 128);
    const float* A  = sentB ? (sel ? sfd : sfm) : (sel ? Av : Am);
    const float* W  = sentB ? (sel ? W4 : W3) : (sel ? W2 : W1);
    const float* Bs = sentB ? (sel ? B4 : B3) : (sel ? B2 : B1);
    float* D = sentB ? (sel ? sv : sm) : (sel ? wv : wm);
    const int R0 = sentB ? 0 : blockIdx.x * 16;
    const int r = tid >> 4;
    const int j0 = (tid & 15) * 8;
    float acc[8] = {0.f,0.f,0.f,0.f,0.f,0.f,0.f,0.f};
    for (int k0 = 0; k0 < 768; k0 += 64) {
        __syncthreads();
#pragma unroll
        for (int it = 0; it < 4; ++it) {
            int f = tid + it * 256;
            int rr = f >> 6, cc = f & 63;
            int rsrc = sentB ? (rr & 7) : rr;
            At[rr][cc] = A[(size_t)(R0 + rsrc) * 768 + k0 + cc];
        }
#pragma unroll
        for (int it = 0; it < 8; ++it) {
            int f = tid + it * 256;
            int rr = f >> 5, c4 = (f & 31) * 4;
            *(float4*)&Wt[rr][c4] = *(const float4*)&W[(size_t)(k0 + rr) * 128 + c4];
        }
        __syncthreads();
#pragma unroll 8
        for (int kk = 0; kk < 64; ++kk) {
            float a = At[r][kk];
            float4 w0 = *(const float4*)&Wt[kk][j0];
            float4 w1 = *(const float4*)&Wt[kk][j0 + 4];
            acc[0] += a * w0.x; acc[1] += a * w0.y; acc[2] += a * w0.z; acc[3] += a * w0.w;
            acc[4] += a * w1.x; acc[5] += a * w1.y; acc[6] += a * w1.z; acc[7] += a * w1.w;
        }
    }
    if (!sentB || r < 8) {
        size_t ob = (size_t)(R0 + r) * 128 + j0;
#pragma unroll
        for (int c = 0; c < 8; ++c) {
            float vl = acc[c] + Bs[j0 + c];
            D[ob + c] = vl;
            tileT[r][j0 + c] = vl;
        }
    }
    if (sel && !sentB) {
        __syncthreads();
        int d = tid >> 1, h = tid & 1;
        unsigned short u[8];
#pragma unroll
        for (int ss = 0; ss < 8; ++ss) u[ss] = f2bf(tileT[h * 8 + ss][d]);
        unsigned int p0 = (unsigned int)u[0] | ((unsigned int)u[1] << 16);
        unsigned int p1 = (unsigned int)u[2] | ((unsigned int)u[3] << 16);
        unsigned int p2 = (unsigned int)u[4] | ((unsigned int)u[5] << 16);
        unsigned int p3 = (unsigned int)u[6] | ((unsigned int)u[7] << 16);
        unsigned short* dst = wvTg + (size_t)(R0 >> 8) * 32768 + (size_t)d * 256 + (R0 & 255) + h * 8;
        *(uint4*)dst = make_uint4(p0, p1, p2, p3);
    }
}

// ---------------------------------------------------------------- batched block reduce (8 waves), one barrier set
template <int N>
__device__ __forceinline__ void bsumN(float* v, float* red) {
#pragma unroll
    for (int o = 32; o; o >>= 1)
#pragma unroll
        for (int n = 0; n < N; ++n) v[n] += __shfl_xor(v[n], o);
    __syncthreads();
    if ((threadIdx.x & 63) == 0) {
        int w = threadIdx.x >> 6;
#pragma unroll
        for (int n = 0; n < N; ++n) red[w * N + n] = v[n];
    }
    __syncthreads();
#pragma unroll
    for (int n = 0; n < N; ++n) {
        float t = 0.f;
#pragma unroll
        for (int w = 0; w < 8; ++w) t += red[w * N + n];
        v[n] = t;
    }
    __syncthreads();
}

// ---------------------------------------------------------------- K4: fully fused. grid 512 = (b,l), block 512 (8 waves).
__global__ __launch_bounds__(512, 2)
void k4_fused(const float* __restrict__ wm, const float* __restrict__ wv,
              const unsigned short* __restrict__ wvTg,
              const float* __restrict__ smg, const float* __restrict__ svg,
              const float* __restrict__ lmg, const float* __restrict__ ldvg,
              float* __restrict__ out) {
    extern __shared__ float smem[];
    float* Amat = smem;                 // 16896 f32 (pre-stage scratch; S^T bf16 staging; Sigma/L/X)
    float* Wb   = smem + 16896;         // 2112 (Sbuf alias in sweeps)
    float* Sbuf = Wb;
    float* ssq  = smem + 19008;         // 256  sqrt(score)
    float* svr  = smem + 19264;         // 128
    float* vrow = smem + 19392;         // 128  label_div row
    float* zv   = smem + 19520;         // 128  (holds mu=label_mean row until delta is built)
    float* zd   = smem + 19648;         // 128
    float* red  = smem + 19776;         // 64
    float* scoreL = Amat;               // 256   (pre-staging only)
    float* part   = Amat + 512;         // 7*512 (pre-staging only)
    float* vpart  = Amat + 4096;        // 16*128 (pre-staging only)

    const int tid = threadIdx.x;
    const int bid = blockIdx.x;
    const int b = bid >> 6, l = bid & 63;

    if (tid < 128) {
        svr[tid]  = svg[b * 128 + tid];
        vrow[tid] = ldvg[l * 128 + tid];
        zv[tid]   = lmg[l * 128 + tid];     // mu (temporary)
    }
    __syncthreads();
    // ---- phase 0a: label scalars
    float lv[3] = {0.f, 0.f, 0.f};
    if (tid < 128) {
        float m = zv[tid], v = vrow[tid];
        lv[0] = m * m; lv[1] = v * v; lv[2] = m * v;
    }
    bsumN<3>(lv, red);
    const float mmp = lv[0], np = 1.f + lv[1], vmp = lv[2];
    // ---- phase 0b: per-row dots + row scalars; 2 threads per row (half-row each)
    {
        int s = tid & 255, h = tid >> 8;
        const float4* wmr = (const float4*)(wm + (size_t)(b * 256 + s) * 128);
        const float4* wvr = (const float4*)(wv + (size_t)(b * 256 + s) * 128);
        float md = 0.f, dot = 0.f, pvv = 0.f, vq = 0.f;
        float smm = 0.f, svv = 0.f, smv = 0.f;
        int q0 = h * 16;
#pragma unroll 8
        for (int qq = 0; qq < 16; ++qq) {
            int q = q0 + qq;
            float4 xm = wmr[q], xv = wvr[q];
            const float* m4 = &zv[q * 4];
            const float* v4 = &vrow[q * 4];
            md  += m4[0] * xm.x + m4[1] * xm.y + m4[2] * xm.z + m4[3] * xm.w;
            dot += v4[0] * xv.x + v4[1] * xv.y + v4[2] * xv.z + v4[3] * xv.w;
            pvv += m4[0] * xv.x + m4[1] * xv.y + m4[2] * xv.z + m4[3] * xv.w;
            vq  += v4[0] * xm.x + v4[1] * xm.y + v4[2] * xm.z + v4[3] * xm.w;
            smm += xm.x * xm.x + xm.y * xm.y + xm.z * xm.z + xm.w * xm.w;
            svv += xv.x * xv.x + xv.y * xv.y + xv.z * xv.z + xv.w * xv.w;
            smv += xm.x * xv.x + xm.y * xv.y + xm.z * xv.z + xm.w * xv.w;
        }
        part[0 * 512 + tid] = md;  part[1 * 512 + tid] = dot;
        part[2 * 512 + tid] = pvv; part[3 * 512 + tid] = vq;
        part[4 * 512 + tid] = smm; part[5 * 512 + tid] = svv;
        part[6 * 512 + tid] = smv;
    }
    __syncthreads();
    float logit = -1e30f;
    if (tid < 256) {
        float md  = part[0 * 512 + tid] + part[0 * 512 + tid + 256];
        float dot = part[1 * 512 + tid] + part[1 * 512 + tid + 256];
        float pvv = part[2 * 512 + tid] + part[2 * 512 + tid + 256];
        float vq  = part[3 * 512 + tid] + part[3 * 512 + tid + 256];
        float smm = part[4 * 512 + tid] + part[4 * 512 + tid + 256];
        float svv = part[5 * 512 + tid] + part[5 * 512 + tid + 256];
        float smv = part[6 * 512 + tid] + part[6 * 512 + tid + 256];
        float nq = 1.f + svv;
        float d2 = smm - 2.f * md + mmp;
        float vqd = smv - pvv, vpd = vq - vmp;
        float inq = 1.f / nq, inp = 1.f / np;
        float maha_q = d2 - vqd * vqd * inq;
        float maha_p = d2 - vpd * vpd * inp;
        logit = 0.25f * ((np - 1.f) + (nq - 1.f)
                         - (nq - 1.f + dot * dot) * inq
                         - (np - 1.f + dot * dot) * inp
                         + maha_q + maha_p);
    }
    // ---- phase 0c: softmax over threads 0..255 (block-wide barriers)
    float mx = logit;
#pragma unroll
    for (int o = 32; o; o >>= 1) mx = fmaxf(mx, __shfl_xor(mx, o));
    if ((tid & 63) == 0) red[tid >> 6] = mx;
    __syncthreads();
    mx = fmaxf(fmaxf(red[0], red[1]), fmaxf(red[2], red[3]));
    float e = (tid < 256) ? expf(logit - mx) : 0.f;
    float s = e;
#pragma unroll
    for (int o = 32; o; o >>= 1) s += __shfl_xor(s, o);
    __syncthreads();
    if ((tid & 63) == 0) red[tid >> 6] = s;
    __syncthreads();
    float tot = red[0] + red[1] + red[2] + red[3];
    if (tid < 256) {
        float sc = e / tot;
        scoreL[tid] = sc;
        ssq[tid] = sqrtf(sc);
    }
    __syncthreads();
    // ---- phase 0d: v_mean = score @ wm (16 s-groups x 128 d)
    {
        int d4 = (tid & 31) * 4, sg = tid >> 5;   // sg 0..15
        const float* wmb = wm + (size_t)b * 256 * 128;
        float ax = 0.f, ay = 0.f, az = 0.f, aw = 0.f;
        for (int s2 = sg * 16; s2 < sg * 16 + 16; ++s2) {
            float w = scoreL[s2];
            float4 x = *(const float4*)&wmb[(size_t)s2 * 128 + d4];
            ax += w * x.x; ay += w * x.y; az += w * x.z; aw += w * x.w;
        }
        *(float4*)&vpart[sg * 128 + d4] = make_float4(ax, ay, az, aw);
    }
    __syncthreads();
    if (tid < 128) {
        float vm8 = 0.f;
#pragma unroll
        for (int g2 = 0; g2 < 16; ++g2) vm8 += vpart[g2 * 128 + tid];
        zd[tid] = zv[tid] - 0.5f * (smg[b * 128 + tid] + vm8);  // delta
        zv[tid] = vrow[tid];                                     // rhs v
    }
    __syncthreads();   // pre-stage scratch dead; Amat free for staging
    // ---- phase 1a: stage S^T (bf16, rows d, 264-bf16 pitch), scaled by sqrt(score)
    {
        unsigned short* Sb = (unsigned short*)Amat;
        const unsigned short* src = wvTg + (size_t)b * 32768;
        const int s0 = (tid & 31) * 8;
        float ssv[8];
#pragma unroll
        for (int j = 0; j < 8; ++j) ssv[j] = ssq[s0 + j];
#pragma unroll
        for (int it = 0; it < 8; ++it) {
            int f8 = tid + it * 512;
            int d = f8 >> 5;
            uint4 raw = *(const uint4*)&src[(size_t)f8 * 8];
            unsigned int p0 = (unsigned int)f2bf(bf2f(raw.x & 0xffffu) * ssv[0])
                            | ((unsigned int)f2bf(bf2f(raw.x >> 16) * ssv[1]) << 16);
            unsigned int p1 = (unsigned int)f2bf(bf2f(raw.y & 0xffffu) * ssv[2])
                            | ((unsigned int)f2bf(bf2f(raw.y >> 16) * ssv[3]) << 16);
            unsigned int p2 = (unsigned int)f2bf(bf2f(raw.z & 0xffffu) * ssv[4])
                            | ((unsigned int)f2bf(bf2f(raw.z >> 16) * ssv[5]) << 16);
            unsigned int p3 = (unsigned int)f2bf(bf2f(raw.w & 0xffffu) * ssv[6])
                            | ((unsigned int)f2bf(bf2f(raw.w >> 16) * ssv[7]) << 16);
            *(uint4*)&Sb[(size_t)d * 264 + s0] = make_uint4(p0, p1, p2, p3);
        }
    }
    __syncthreads();
    // ---- phase 1b: M = S^T S via MFMA; wave w computes tile-row w (8 tiles)
    {
        const unsigned short* Sb = (const unsigned short*)Amat;
        const int w = tid >> 6, ln = tid & 63;
        const int rl = ln & 15, g = ln >> 4;
        const int arow = 16 * w + rl;
        f32x4 acc[8];
#pragma unroll
        for (int t = 0; t < 8; ++t) acc[t] = (f32x4){0.f, 0.f, 0.f, 0.f};
#pragma unroll
        for (int ks = 0; ks < 8; ++ks) {
            bf16x8 a = *(const bf16x8*)&Sb[(size_t)arow * 264 + ks * 32 + g * 8];
#pragma unroll
            for (int tj = 0; tj < 8; ++tj) {
                bf16x8 bb = *(const bf16x8*)&Sb[(size_t)(16 * tj + rl) * 264 + ks * 32 + g * 8];
                acc[tj] = __builtin_amdgcn_mfma_f32_16x16x32_bf16(a, bb, acc[tj], 0, 0, 0);
            }
        }
        __syncthreads();   // all MFMA reads done; overwrite with Sigma f32
#pragma unroll
        for (int tj = 0; tj < 8; ++tj) {
            int j = 16 * tj + rl;
            float svj = svr[j];
#pragma unroll
            for (int r = 0; r < 4; ++r) {
                int i = 16 * w + g * 4 + r;
                Amat[i * PITCH + j] = ((i == j) ? 1.f : 0.f) + 0.5f * (svr[i] * svj + acc[tj][r]);
            }
        }
    }
    __syncthreads();
    // ---- phase 2c: label-side closed-form terms, one batched reduction
    float v5[5] = {0.f, 0.f, 0.f, 0.f, 0.f};
    if (tid < 128) {
        v5[0] = Amat[tid * PITCH + tid];
        float vv = vrow[tid], de = zd[tid];
        v5[1] = vv * vv; v5[2] = de * de; v5[3] = vv * de;
    }
    {
        int i = tid >> 2, sg2 = (tid & 3) * 32;
        const float* Ar = &Amat[i * PITCH + sg2];
        const float* vr = &vrow[sg2];
        float s2 = 0.f;
        for (int k2 = 0; k2 < 32; k2 += 4) {
            float4 a = *(const float4*)&Ar[k2];
            s2 += a.x * vr[k2] + a.y * vr[k2 + 1] + a.z * vr[k2 + 2] + a.w * vr[k2 + 3];
        }
        v5[4] = vrow[i] * s2;
    }
    bsumN<5>(v5, red);
    const float trP = v5[0], nv = v5[1], dds = v5[2], vds = v5[3], vsv = v5[4];
    // ---- phase 3: blocked Cholesky, panel width 16; Schur on LOWER tiles only
    for (int p = 0; p < 8; ++p) {
        const int base = 16 * p;
        __syncthreads();
        if (tid < 64) {
            const int c = tid;
            float cv[16];
            if (c < 16) {
#pragma unroll
                for (int r = 0; r < 16; ++r) {
                    int hi = (r >= c) ? r : c, lo2 = (r >= c) ? c : r;
                    cv[r] = Amat[(base + hi) * PITCH + base + lo2];
                }
            } else {
#pragma unroll
                for (int r = 0; r < 16; ++r) cv[r] = 0.f;
            }
#pragma unroll
            for (int t = 0; t < 16; ++t) {
                float lt[16];
#pragma unroll
                for (int r = 0; r < 16; ++r) lt[r] = __shfl(cv[r], t);
                float invs = 1.f / sqrtf(lt[t]);
                if (c == t) {
#pragma unroll
                    for (int r = 0; r < 16; ++r) cv[r] = (r >= t) ? lt[r] * invs : 0.f;
                } else if (c > t && c < 16) {
                    float lc = lt[c] * invs;
#pragma unroll
                    for (int r = 0; r < 16; ++r)
                        if (r > t) cv[r] -= (lt[r] * invs) * lc;
                }
            }
            float x[16], acb[16];
#pragma unroll
            for (int r = 0; r < 16; ++r) acb[r] = 0.f;
#pragma unroll
            for (int r = 0; r < 16; ++r) {
                float Lrr = __shfl(cv[r], r);
                float xr = (((c == r) ? 1.f : 0.f) - acb[r]) / Lrr;
                x[r] = xr;
#pragma unroll
                for (int q = r + 1; q < 16; ++q) acb[q] += __shfl(cv[q], r) * xr;
            }
            if (c < 16) {
#pragma unroll
                for (int r = 0; r < 16; ++r)
                    Amat[(base + c) * PITCH + base + r] = x[r];   // T^T into diag block
            }
            if (c < 32) {
                int t2 = c & 15;
                float* zp = (c < 16) ? zv : zd;
                float a0 = 0.f;
#pragma unroll
                for (int a = 0; a < 16; ++a)
                    a0 += Amat[(base + a) * PITCH + base + t2] * zp[base + a];
                zp[base + t2] = a0;
            }
        }
        __syncthreads();
        const int R = 112 - base;
        if (R > 0 && tid < R) {
            int i = base + 16 + tid;
            const float* Ar = &Amat[i * PITCH + base];
            float4 q0 = *(const float4*)&Ar[0];
            float4 q1 = *(const float4*)&Ar[4];
            float4 q2 = *(const float4*)&Ar[8];
            float4 q3 = *(const float4*)&Ar[12];
            float rA[16] = {q0.x,q0.y,q0.z,q0.w, q1.x,q1.y,q1.z,q1.w,
                            q2.x,q2.y,q2.z,q2.w, q3.x,q3.y,q3.z,q3.w};
            float lo[16];
#pragma unroll
            for (int t = 0; t < 16; ++t) lo[t] = 0.f;
#pragma unroll
            for (int a = 0; a < 16; ++a) {
                float va = rA[a];
                const float* Trow = &Amat[(base + a) * PITCH + base];
                float4 t0 = *(const float4*)&Trow[0];
                float4 t1 = *(const float4*)&Trow[4];
                float4 t2 = *(const float4*)&Trow[8];
                float4 t3 = *(const float4*)&Trow[12];
                lo[0] += va * t0.x; lo[1] += va * t0.y; lo[2] += va * t0.z; lo[3] += va * t0.w;
                lo[4] += va * t1.x; lo[5] += va * t1.y; lo[6] += va * t1.z; lo[7] += va * t1.w;
                lo[8] += va * t2.x; lo[9] += va * t2.y; lo[10] += va * t2.z; lo[11] += va * t2.w;
                lo[12] += va * t3.x; lo[13] += va * t3.y; lo[14] += va * t3.z; lo[15] += va * t3.w;
            }
            float* Aw = &Amat[i * PITCH + base];
            *(float4*)&Aw[0]  = make_float4(lo[0], lo[1], lo[2], lo[3]);
            *(float4*)&Aw[4]  = make_float4(lo[4], lo[5], lo[6], lo[7]);
            *(float4*)&Aw[8]  = make_float4(lo[8], lo[9], lo[10], lo[11]);
            *(float4*)&Aw[12] = make_float4(lo[12], lo[13], lo[14], lo[15]);
#pragma unroll
            for (int t = 0; t < 16; ++t) Wb[t * PITCH + i] = lo[t];
        }
        __syncthreads();
        if (R > 0) {
            if (tid >= base + 16 && tid < 128) {
                int i = tid;
                const float* Lr = &Amat[i * PITCH + base];
                float dv = 0.f, dd2 = 0.f;
#pragma unroll
                for (int t = 0; t < 16; ++t) {
                    float lvv = Lr[t];
                    dv  += lvv * zv[base + t];
                    dd2 += lvv * zd[base + t];
                }
                zv[i] -= dv; zd[i] -= dd2;
            }
            int nt = R >> 3;
            int ntri = (nt * (nt + 1)) >> 1;
            for (int tau = tid; tau < ntri; tau += 512) {
                float ft = sqrtf(8.f * (float)tau + 1.f);
                int tr = (int)((ft - 1.f) * 0.5f);
                while (((tr + 1) * (tr + 2)) / 2 <= tau) ++tr;
                while ((tr * (tr + 1)) / 2 > tau) --tr;
                int tc = tau - ((tr * (tr + 1)) >> 1);
                int ii = base + 16 + tr * 8, jj = base + 16 + tc * 8;
                float a2[8][8];
#pragma unroll
                for (int r = 0; r < 8; ++r)
#pragma unroll
                    for (int c = 0; c < 8; ++c) a2[r][c] = 0.f;
#pragma unroll
                for (int t = 0; t < 16; ++t) {
                    const float* wr = &Wb[t * PITCH];
                    float4 x0 = *(const float4*)&wr[ii];
                    float4 x1 = *(const float4*)&wr[ii + 4];
                    float4 y0 = *(const float4*)&wr[jj];
                    float4 y1 = *(const float4*)&wr[jj + 4];
                    float xa[8] = {x0.x,x0.y,x0.z,x0.w, x1.x,x1.y,x1.z,x1.w};
                    float yb[8] = {y0.x,y0.y,y0.z,y0.w, y1.x,y1.y,y1.z,y1.w};
#pragma unroll
                    for (int r = 0; r < 8; ++r)
#pragma unroll
                        for (int c = 0; c < 8; ++c) a2[r][c] += xa[r] * yb[c];
                }
#pragma unroll
                for (int r = 0; r < 8; ++r) {
                    float* Ar2 = &Amat[(ii + r) * PITCH + jj];
                    float4 u0 = *(float4*)&Ar2[0];
                    float4 u1 = *(float4*)&Ar2[4];
                    u0.x -= a2[r][0]; u0.y -= a2[r][1]; u0.z -= a2[r][2]; u0.w -= a2[r][3];
                    u1.x -= a2[r][4]; u1.y -= a2[r][5]; u1.z -= a2[r][6]; u1.w -= a2[r][7];
                    *(float4*)&Ar2[0] = u0;
                    *(float4*)&Ar2[4] = u1;
                }
            }
        }
    }
    // ---- phase 3b: X = L^{-1} via 7 block-sweeps; 4x4 register tiles
    for (int s2 = 1; s2 <= 7; ++s2) {
        __syncthreads();
        int npair = 8 - s2;
        int jobs = npair * 16;
        int len = 16 * s2;
        for (int t = tid; t < jobs; t += 512) {
            int pr = t >> 4;
            int ta = (t >> 2) & 3, tb = t & 3;
            int i = pr + s2, J = pr;
            const float* u0 = &Amat[(16 * i + ta * 4) * PITCH + 16 * J];
            const float* w0 = &Amat[(16 * J + tb * 4) * PITCH + 16 * J];
            float a4[4][4];
#pragma unroll
            for (int r = 0; r < 4; ++r)
#pragma unroll
                for (int c = 0; c < 4; ++c) a4[r][c] = 0.f;
            for (int k = 0; k < len; k += 4) {
                float4 ur[4], wr4[4];
#pragma unroll
                for (int r = 0; r < 4; ++r) ur[r] = *(const float4*)&u0[r * PITCH + k];
#pragma unroll
                for (int c = 0; c < 4; ++c) wr4[c] = *(const float4*)&w0[c * PITCH + k];
#pragma unroll
                for (int r = 0; r < 4; ++r)
#pragma unroll
                    for (int c = 0; c < 4; ++c)
                        a4[r][c] += ur[r].x * wr4[c].x + ur[r].y * wr4[c].y
                                  + ur[r].z * wr4[c].z + ur[r].w * wr4[c].w;
            }
#pragma unroll
            for (int r = 0; r < 4; ++r)
#pragma unroll
                for (int c = 0; c < 4; ++c)
                    Sbuf[pr * 256 + (ta * 4 + r) * 16 + tb * 4 + c] = a4[r][c];
        }
        __syncthreads();
        for (int idx = tid; idx < npair * 256; idx += 512) {
            int pr = idx >> 8;
            int J = pr, i = pr + s2;
            int cc = (idx >> 4) & 15, bb = idx & 15;
            float a0 = 0.f;
#pragma unroll
            for (int a = 0; a < 16; ++a)
                a0 += Amat[(16 * i + a) * PITCH + 16 * i + cc] * Sbuf[pr * 256 + a * 16 + bb];
            Amat[(16 * J + bb) * PITCH + 16 * i + cc] = -a0;
        }
    }
    __syncthreads();
    // ---- phase 4: trinv, qv, qd (one batched reduction)
    float v3[3] = {0.f, 0.f, 0.f};
    {
        int i = tid & 127, h = tid >> 7;          // h 0..3
        int c0 = (i >> 4) << 4;
        int quar = (128 - c0) >> 2;               // multiple of 4
        const float* Ar = &Amat[i * PITCH + c0 + h * quar];
        for (int k2 = 0; k2 < quar; k2 += 4) {
            float4 a = *(const float4*)&Ar[k2];
            v3[0] += a.x * a.x + a.y * a.y + a.z * a.z + a.w * a.w;
        }
    }
    if (tid < 128) {
        float a = zv[tid];  v3[1] = a * a;
        float d22 = zd[tid]; v3[2] = d22 * d22;
    }
    bsumN<3>(v3, red);
    if (tid == 0) {
        float n = 1.f + nv;
        float Aterm = trP - vsv / n;              // tr(Sq^{-1} Sp)
        float Bt = v3[0] + v3[1];                 // tr(Sp^{-1} Sq)
        float mq = dds - vds * vds / n;           // delta^T Sq^{-1} delta
        out[bid] = 0.25f * (Aterm + Bt - 256.f + mq + v3[2]);
    }
    // ---- phase 5: broadcast outputs lm_b[b][l], lc_b[b][l]
    if (tid < 32) {
        float4 v = *(const float4*)&lmg[l * 128 + tid * 4];
        *(float4*)&out[512 + (size_t)bid * 128 + tid * 4] = v;
    }
    {
        float* lcb = out + 512 + 65536 + (size_t)bid * 16384;
#pragma unroll
        for (int q = 0; q < 8; ++q) {
            int flat4 = q * 512 + tid;
            int i = flat4 >> 5;
            int j4 = (flat4 & 31) * 4;
            float vi = vrow[i];
            float4 r;
            r.x = vi * vrow[j4 + 0] + ((i == j4 + 0) ? 1.f : 0.f);
            r.y = vi * vrow[j4 + 1] + ((i == j4 + 1) ? 1.f : 0.f);
            r.z = vi * vrow[j4 + 2] + ((i == j4 + 2) ? 1.f : 0.f);
            r.w = vi * vrow[j4 + 3] + ((i == j4 + 3) ? 1.f : 0.f);
            *(float4*)&lcb[(size_t)flat4 * 4] = r;
        }
    }
}

// ---------------------------------------------------------------- launch
extern "C" void kernel_launch(void* const* d_in, const int* in_sizes, int n_in,
                              void* d_out, int out_size, void* d_ws, size_t ws_size,
                              hipStream_t stream) {
    const float* wfm = (const float*)d_in[0];
    const float* wfd = (const float*)d_in[1];
    const float* sfm = (const float*)d_in[2];
    const float* sfd = (const float*)d_in[3];
    const float* W1 = (const float*)d_in[4];
    const float* B1 = (const float*)d_in[5];
    const float* W2 = (const float*)d_in[6];
    const float* B2 = (const float*)d_in[7];
    const float* W3 = (const float*)d_in[8];
    const float* B3 = (const float*)d_in[9];
    const float* W4 = (const float*)d_in[10];
    const float* B4 = (const float*)d_in[11];
    const float* lm = (const float*)d_in[12];
    const float* ldv = (const float*)d_in[13];
    float* out = (float*)d_out;
    float* ws = (float*)d_ws;

    float* wm = ws;                           // 262144
    float* wv = ws + 262144;                  // 262144
    float* sm = ws + 524288;                  // 1024
    float* sv = ws + 525312;                  // 1024
    unsigned short* wvTg = (unsigned short*)(ws + 731392);  // 262144 bf16

    constexpr int SH_FLOATS = 19840;
    constexpr size_t SH_BYTES = SH_FLOATS * sizeof(float);   // 79360 B -> 2 blocks/CU (158.7KB/160KB)
    (void)hipFuncSetAttribute((const void*)k4_fused,
                              hipFuncAttributeMaxDynamicSharedMemorySize,
                              (int)SH_BYTES);

    k1_gemm<<<dim3(129, 2), 256, 0, stream>>>(wfm, wfd, sfm, sfd,
                                              W1, B1, W2, B2, W3, B3, W4, B4,
                                              wm, wv, sm, sv, wvTg);
    k4_fused<<<512, 512, SH_BYTES, stream>>>(wm, wv, wvTg, sm, sv, lm, ldv, out);
}

// Round 9
// 212.222 us; speedup vs baseline: 1.5514x; 1.5514x over previous
//
#include <hip/hip_runtime.h>
#include <hip/hip_bf16.h>

// B=8 S=256 H=768 D=128 L=64, all inputs f32.
// Outputs: relate_score (8*64) | lm_b (8*64*128) | lc_b (8*64*128*128), f32.

#define PITCH 132

typedef __attribute__((ext_vector_type(8))) short bf16x8;
typedef __attribute__((ext_vector_type(4))) float f32x4;

__device__ __forceinline__ float bf2f(unsigned int u) {
    union { unsigned int i; float f; } c; c.i = u << 16; return c.f;
}
__device__ __forceinline__ unsigned short f2bf(float f) {
    __hip_bfloat16 h = __float2bfloat16(f);
    union { __hip_bfloat16 h; unsigned short u; } c; c.h = h; return c.u;
}

// ---------------------------------------------------------------- K1: wm/wv GEMM (+ bf16 wv^T) + sm/sv (blockIdx.x==128)
__global__ __launch_bounds__(256, 2)
void k1_gemm(const float* __restrict__ Am, const float* __restrict__ Av,
             const float* __restrict__ sfm, const float* __restrict__ sfd,
             const float* __restrict__ W1, const float* __restrict__ B1,
             const float* __restrict__ W2, const float* __restrict__ B2,
             const float* __restrict__ W3, const float* __restrict__ B3,
             const float* __restrict__ W4, const float* __restrict__ B4,
             float* __restrict__ wm, float* __restrict__ wv,
             float* __restrict__ sm, float* __restrict__ sv,
             unsigned short* __restrict__ wvTg) {
    __shared__ float At[16][64];
    __shared__ __align__(16) float Wt[64][128];
    __shared__ float tileT[16][129];
    const int tid = threadIdx.x;
    const int sel = blockIdx.y;
    const bool sentB = (blockIdx.x == 128);
    const float* A  = sentB ? (sel ? sfd : sfm) : (sel ? Av : Am);
    const float* W  = sentB ? (sel ? W4 : W3) : (sel ? W2 : W1);
    const float* Bs = sentB ? (sel ? B4 : B3) : (sel ? B2 : B1);
    float* D = sentB ? (sel ? sv : sm) : (sel ? wv : wm);
    const int R0 = sentB ? 0 : blockIdx.x * 16;
    const int r = tid >> 4;
    const int j0 = (tid & 15) * 8;
    float acc[8] = {0.f,0.f,0.f,0.f,0.f,0.f,0.f,0.f};
    for (int k0 = 0; k0 < 768; k0 += 64) {
        __syncthreads();
#pragma unroll
        for (int it = 0; it < 4; ++it) {
            int f = tid + it * 256;
            int rr = f >> 6, cc = f & 63;
            int rsrc = sentB ? (rr & 7) : rr;
            At[rr][cc] = A[(size_t)(R0 + rsrc) * 768 + k0 + cc];
        }
#pragma unroll
        for (int it = 0; it < 8; ++it) {
            int f = tid + it * 256;
            int rr = f >> 5, c4 = (f & 31) * 4;
            *(float4*)&Wt[rr][c4] = *(const float4*)&W[(size_t)(k0 + rr) * 128 + c4];
        }
        __syncthreads();
#pragma unroll 8
        for (int kk = 0; kk < 64; ++kk) {
            float a = At[r][kk];
            float4 w0 = *(const float4*)&Wt[kk][j0];
            float4 w1 = *(const float4*)&Wt[kk][j0 + 4];
            acc[0] += a * w0.x; acc[1] += a * w0.y; acc[2] += a * w0.z; acc[3] += a * w0.w;
            acc[4] += a * w1.x; acc[5] += a * w1.y; acc[6] += a * w1.z; acc[7] += a * w1.w;
        }
    }
    if (!sentB || r < 8) {
        size_t ob = (size_t)(R0 + r) * 128 + j0;
#pragma unroll
        for (int c = 0; c < 8; ++c) {
            float vl = acc[c] + Bs[j0 + c];
            D[ob + c] = vl;
            tileT[r][j0 + c] = vl;
        }
    }
    if (sel && !sentB) {
        __syncthreads();
        int d = tid >> 1, h = tid & 1;
        unsigned short u[8];
#pragma unroll
        for (int ss = 0; ss < 8; ++ss) u[ss] = f2bf(tileT[h * 8 + ss][d]);
        unsigned int p0 = (unsigned int)u[0] | ((unsigned int)u[1] << 16);
        unsigned int p1 = (unsigned int)u[2] | ((unsigned int)u[3] << 16);
        unsigned int p2 = (unsigned int)u[4] | ((unsigned int)u[5] << 16);
        unsigned int p3 = (unsigned int)u[6] | ((unsigned int)u[7] << 16);
        unsigned short* dst = wvTg + (size_t)(R0 >> 8) * 32768 + (size_t)d * 256 + (R0 & 255) + h * 8;
        *(uint4*)dst = make_uint4(p0, p1, p2, p3);
    }
}

// ---------------------------------------------------------------- batched block reduce (4 waves), one barrier set
template <int N>
__device__ __forceinline__ void bsumN(float* v, float* red) {
#pragma unroll
    for (int o = 32; o; o >>= 1)
#pragma unroll
        for (int n = 0; n < N; ++n) v[n] += __shfl_xor(v[n], o);
    __syncthreads();
    if ((threadIdx.x & 63) == 0) {
        int w = threadIdx.x >> 6;
#pragma unroll
        for (int n = 0; n < N; ++n) red[w * N + n] = v[n];
    }
    __syncthreads();
#pragma unroll
    for (int n = 0; n < N; ++n)
        v[n] = red[0 * N + n] + red[1 * N + n] + red[2 * N + n] + red[3 * N + n];
    __syncthreads();
}

// ---------------------------------------------------------------- K4: fully fused; lookahead Cholesky. grid 512 = (b,l), block 256.
__global__ __launch_bounds__(256, 2)
void k4_fused(const float* __restrict__ wm, const float* __restrict__ wv,
              const unsigned short* __restrict__ wvTg,
              const float* __restrict__ smg, const float* __restrict__ svg,
              const float* __restrict__ lmg, const float* __restrict__ ldvg,
              float* __restrict__ out) {
    extern __shared__ float smem[];
    float* Amat = smem;                 // 16896 f32 (pre-stage scratch; S^T bf16 staging; Sigma/L/X)
    float* Wb   = smem + 16896;         // 2112 (Sbuf alias in sweeps)
    float* Sbuf = Wb;
    float* ssq  = smem + 19008;         // 256  sqrt(score)
    float* svr  = smem + 19264;         // 128
    float* vrow = smem + 19392;         // 128  label_div row
    float* zv   = smem + 19520;         // 128  (holds mu=label_mean row until delta is built)
    float* zd   = smem + 19648;         // 128
    float* red  = smem + 19776;         // 24
    float* scoreL = Amat;               // 256 (pre-staging only)
    float* vpart  = Amat + 256;         // 1024 (pre-staging only)

    const int tid = threadIdx.x;
    const int bid = blockIdx.x;
    const int b = bid >> 6, l = bid & 63;

    if (tid < 128) {
        svr[tid]  = svg[b * 128 + tid];
        vrow[tid] = ldvg[l * 128 + tid];
        zv[tid]   = lmg[l * 128 + tid];     // mu (temporary)
    }
    __syncthreads();
    // ---- early output writes: lm_b[b][l], lc_b[b][l] (depend only on lmg/vrow;
    //      issued first so the stores drain under all subsequent compute)
    if (tid < 32) {
        float4 v = *(const float4*)&lmg[l * 128 + tid * 4];
        *(float4*)&out[512 + (size_t)bid * 128 + tid * 4] = v;
    }
    {
        float* lcb = out + 512 + 65536 + (size_t)bid * 16384;
#pragma unroll
        for (int q = 0; q < 16; ++q) {
            int flat4 = q * 256 + tid;
            int i = flat4 >> 5;
            int j4 = (flat4 & 31) * 4;
            float vi = vrow[i];
            float4 r;
            r.x = vi * vrow[j4 + 0] + ((i == j4 + 0) ? 1.f : 0.f);
            r.y = vi * vrow[j4 + 1] + ((i == j4 + 1) ? 1.f : 0.f);
            r.z = vi * vrow[j4 + 2] + ((i == j4 + 2) ? 1.f : 0.f);
            r.w = vi * vrow[j4 + 3] + ((i == j4 + 3) ? 1.f : 0.f);
            *(float4*)&lcb[(size_t)flat4 * 4] = r;
        }
    }
    // ---- phase 0a: label scalars
    float lv[3] = {0.f, 0.f, 0.f};
    if (tid < 128) {
        float m = zv[tid], v = vrow[tid];
        lv[0] = m * m; lv[1] = v * v; lv[2] = m * v;
    }
    bsumN<3>(lv, red);
    const float mmp = lv[0], np = 1.f + lv[1], vmp = lv[2];
    // ---- phase 0b: per-row dots + row scalars (thread = s)
    const float4* wmr = (const float4*)(wm + (size_t)(b * 256 + tid) * 128);
    const float4* wvr = (const float4*)(wv + (size_t)(b * 256 + tid) * 128);
    float md = 0.f, dot = 0.f, pvv = 0.f, vq = 0.f;
    float smm = 0.f, svv = 0.f, smv = 0.f;
#pragma unroll 8
    for (int q = 0; q < 32; ++q) {
        float4 xm = wmr[q], xv = wvr[q];
        const float* m4 = &zv[q * 4];
        const float* v4 = &vrow[q * 4];
        md  += m4[0] * xm.x + m4[1] * xm.y + m4[2] * xm.z + m4[3] * xm.w;
        dot += v4[0] * xv.x + v4[1] * xv.y + v4[2] * xv.z + v4[3] * xv.w;
        pvv += m4[0] * xv.x + m4[1] * xv.y + m4[2] * xv.z + m4[3] * xv.w;
        vq  += v4[0] * xm.x + v4[1] * xm.y + v4[2] * xm.z + v4[3] * xm.w;
        smm += xm.x * xm.x + xm.y * xm.y + xm.z * xm.z + xm.w * xm.w;
        svv += xv.x * xv.x + xv.y * xv.y + xv.z * xv.z + xv.w * xv.w;
        smv += xm.x * xv.x + xm.y * xv.y + xm.z * xv.z + xm.w * xv.w;
    }
    float nq = 1.f + svv;
    float d2 = smm - 2.f * md + mmp;
    float vqd = smv - pvv, vpd = vq - vmp;
    float inq = 1.f / nq, inp = 1.f / np;
    float maha_q = d2 - vqd * vqd * inq;
    float maha_p = d2 - vpd * vpd * inp;
    float logit = 0.25f * ((np - 1.f) + (nq - 1.f)
                           - (nq - 1.f + dot * dot) * inq
                           - (np - 1.f + dot * dot) * inp
                           + maha_q + maha_p);
    // ---- phase 0c: softmax over 256 threads
    float mx = logit;
#pragma unroll
    for (int o = 32; o; o >>= 1) mx = fmaxf(mx, __shfl_xor(mx, o));
    if ((tid & 63) == 0) red[tid >> 6] = mx;
    __syncthreads();
    mx = fmaxf(fmaxf(red[0], red[1]), fmaxf(red[2], red[3]));
    float e = expf(logit - mx);
    float s = e;
#pragma unroll
    for (int o = 32; o; o >>= 1) s += __shfl_xor(s, o);
    __syncthreads();
    if ((tid & 63) == 0) red[tid >> 6] = s;
    __syncthreads();
    float tot = red[0] + red[1] + red[2] + red[3];
    float sc = e / tot;
    scoreL[tid] = sc;
    ssq[tid] = sqrtf(sc);
    __syncthreads();
    // ---- phase 0d: v_mean = score @ wm
    {
        int d4 = (tid & 31) * 4, sg = tid >> 5;
        const float* wmb = wm + (size_t)b * 256 * 128;
        float ax = 0.f, ay = 0.f, az = 0.f, aw = 0.f;
        for (int s2 = sg * 32; s2 < sg * 32 + 32; ++s2) {
            float w = scoreL[s2];
            float4 x = *(const float4*)&wmb[(size_t)s2 * 128 + d4];
            ax += w * x.x; ay += w * x.y; az += w * x.z; aw += w * x.w;
        }
        *(float4*)&vpart[sg * 128 + d4] = make_float4(ax, ay, az, aw);
    }
    __syncthreads();
    if (tid < 128) {
        float vm8 = 0.f;
#pragma unroll
        for (int g2 = 0; g2 < 8; ++g2) vm8 += vpart[g2 * 128 + tid];
        zd[tid] = zv[tid] - 0.5f * (smg[b * 128 + tid] + vm8);  // delta
        zv[tid] = vrow[tid];                                     // rhs v
    }
    __syncthreads();   // pre-stage scratch dead; Amat free for staging
    // ---- phase 1a: stage S^T (bf16, rows d, 264-bf16 pitch), scaled by sqrt(score)
    {
        unsigned short* Sb = (unsigned short*)Amat;
        const unsigned short* src = wvTg + (size_t)b * 32768;
        const int s0 = (tid & 31) * 8;
        float ssv[8];
#pragma unroll
        for (int j = 0; j < 8; ++j) ssv[j] = ssq[s0 + j];
#pragma unroll
        for (int it = 0; it < 16; ++it) {
            int f8 = tid + it * 256;
            int d = f8 >> 5;
            uint4 raw = *(const uint4*)&src[(size_t)f8 * 8];
            unsigned int p0 = (unsigned int)f2bf(bf2f(raw.x & 0xffffu) * ssv[0])
                            | ((unsigned int)f2bf(bf2f(raw.x >> 16) * ssv[1]) << 16);
            unsigned int p1 = (unsigned int)f2bf(bf2f(raw.y & 0xffffu) * ssv[2])
                            | ((unsigned int)f2bf(bf2f(raw.y >> 16) * ssv[3]) << 16);
            unsigned int p2 = (unsigned int)f2bf(bf2f(raw.z & 0xffffu) * ssv[4])
                            | ((unsigned int)f2bf(bf2f(raw.z >> 16) * ssv[5]) << 16);
            unsigned int p3 = (unsigned int)f2bf(bf2f(raw.w & 0xffffu) * ssv[6])
                            | ((unsigned int)f2bf(bf2f(raw.w >> 16) * ssv[7]) << 16);
            *(uint4*)&Sb[(size_t)d * 264 + s0] = make_uint4(p0, p1, p2, p3);
        }
    }
    __syncthreads();
    // ---- phase 1b: M = S^T S via MFMA; wave w computes tile-rows w and w+4
    {
        const unsigned short* Sb = (const unsigned short*)Amat;
        const int w = tid >> 6, ln = tid & 63;
        const int rl = ln & 15, g = ln >> 4;
        const int arow0 = 16 * w + rl;
        const int arow1 = 16 * (w + 4) + rl;
        f32x4 acc0[8], acc1[8];
#pragma unroll
        for (int t = 0; t < 8; ++t) {
            acc0[t] = (f32x4){0.f, 0.f, 0.f, 0.f};
            acc1[t] = (f32x4){0.f, 0.f, 0.f, 0.f};
        }
#pragma unroll
        for (int ks = 0; ks < 8; ++ks) {
            bf16x8 a0 = *(const bf16x8*)&Sb[(size_t)arow0 * 264 + ks * 32 + g * 8];
            bf16x8 a1 = *(const bf16x8*)&Sb[(size_t)arow1 * 264 + ks * 32 + g * 8];
#pragma unroll
            for (int tj = 0; tj < 8; ++tj) {
                bf16x8 bb = *(const bf16x8*)&Sb[(size_t)(16 * tj + rl) * 264 + ks * 32 + g * 8];
                acc0[tj] = __builtin_amdgcn_mfma_f32_16x16x32_bf16(a0, bb, acc0[tj], 0, 0, 0);
                acc1[tj] = __builtin_amdgcn_mfma_f32_16x16x32_bf16(a1, bb, acc1[tj], 0, 0, 0);
            }
        }
        __syncthreads();   // all MFMA reads done; overwrite with Sigma f32
#pragma unroll
        for (int tj = 0; tj < 8; ++tj) {
            int j = 16 * tj + rl;
            float svj = svr[j];
#pragma unroll
            for (int r = 0; r < 4; ++r) {
                int i = 16 * w + g * 4 + r;
                Amat[i * PITCH + j] = ((i == j) ? 1.f : 0.f) + 0.5f * (svr[i] * svj + acc0[tj][r]);
                int i2 = 16 * (w + 4) + g * 4 + r;
                Amat[i2 * PITCH + j] = ((i2 == j) ? 1.f : 0.f) + 0.5f * (svr[i2] * svj + acc1[tj][r]);
            }
        }
    }
    __syncthreads();
    // ---- phase 2c: label-side closed-form terms, one batched reduction
    float v5[5] = {0.f, 0.f, 0.f, 0.f, 0.f};
    if (tid < 128) {
        v5[0] = Amat[tid * PITCH + tid];
        float vv = vrow[tid], de = zd[tid];
        v5[1] = vv * vv; v5[2] = de * de; v5[3] = vv * de;
    }
    {
        int i = tid >> 1, h = tid & 1;
        const float* Ar = &Amat[i * PITCH + h * 64];
        const float* vr = &vrow[h * 64];
        float s2 = 0.f;
        for (int k2 = 0; k2 < 64; k2 += 4) {
            float4 a = *(const float4*)&Ar[k2];
            s2 += a.x * vr[k2] + a.y * vr[k2 + 1] + a.z * vr[k2 + 2] + a.w * vr[k2 + 3];
        }
        v5[4] = vrow[i] * s2;
    }
    bsumN<5>(v5, red);
    const float trP = v5[0], nv = v5[1], dds = v5[2], vds = v5[3], vsv = v5[4];
    // ---- phase 3: blocked Cholesky with LOOKAHEAD.
    // iter p: (1) apply prev panel's rank-16 to col-panel p (+z);  barrier;
    //         (2) F1(p) on wave0  ||  U_rest(prev) on waves 1-3;   barrier;
    //         (3) panel solve p (writes L cols p + Wb).            [3 barriers/panel]
    for (int p = 0; p < 8; ++p) {
        const int base = 16 * p;
        const int R = 112 - base;
        __syncthreads();                         // (a) prev panel-solve visible
        if (p > 0) {
            const int pb = base - 16;
            if (tid >= base && tid < 128) {      // z-update from prev panel
                int i = tid;
                const float* Lr = &Amat[i * PITCH + pb];
                float dv = 0.f, dd2 = 0.f;
#pragma unroll
                for (int t = 0; t < 16; ++t) {
                    float lvv = Lr[t];
                    dv  += lvv * zv[pb + t];
                    dd2 += lvv * zd[pb + t];
                }
                zv[i] -= dv; zd[i] -= dd2;
            }
            // U_col: cols [base,base+16), rows >= base, lower (j<=i) only
            int njobs = (R + 16) * 16;
            for (int idx = tid; idx < njobs; idx += 256) {
                int r2 = idx >> 4, jc = idx & 15;
                int i = base + r2, j = base + jc;
                if (j <= i) {
                    const float* wi = &Wb[i];
                    const float* wj = &Wb[j];
                    float acc2 = 0.f;
#pragma unroll
                    for (int t = 0; t < 16; ++t)
                        acc2 += wi[t * PITCH] * wj[t * PITCH];
                    Amat[i * PITCH + j] -= acc2;
                }
            }
        }
        __syncthreads();                         // (b) col-panel p fully updated
        if (tid < 64) {
            // F1: in-register chol of diag block p + T = Lpp^{-1} + z' transform
            const int c = tid;
            float cv[16];
            if (c < 16) {
#pragma unroll
                for (int r2 = 0; r2 < 16; ++r2) {
                    int hi = (r2 >= c) ? r2 : c, lo2 = (r2 >= c) ? c : r2;
                    cv[r2] = Amat[(base + hi) * PITCH + base + lo2];
                }
            } else {
#pragma unroll
                for (int r2 = 0; r2 < 16; ++r2) cv[r2] = 0.f;
            }
#pragma unroll
            for (int t = 0; t < 16; ++t) {
                float lt[16];
#pragma unroll
                for (int r2 = 0; r2 < 16; ++r2) lt[r2] = __shfl(cv[r2], t);
                float invs = 1.f / sqrtf(lt[t]);
                if (c == t) {
#pragma unroll
                    for (int r2 = 0; r2 < 16; ++r2) cv[r2] = (r2 >= t) ? lt[r2] * invs : 0.f;
                } else if (c > t && c < 16) {
                    float lc = lt[c] * invs;
#pragma unroll
                    for (int r2 = 0; r2 < 16; ++r2)
                        if (r2 > t) cv[r2] -= (lt[r2] * invs) * lc;
                }
            }
            float x[16], acb[16];
#pragma unroll
            for (int r2 = 0; r2 < 16; ++r2) acb[r2] = 0.f;
#pragma unroll
            for (int r2 = 0; r2 < 16; ++r2) {
                float Lrr = __shfl(cv[r2], r2);
                float xr = (((c == r2) ? 1.f : 0.f) - acb[r2]) / Lrr;
                x[r2] = xr;
#pragma unroll
                for (int q = r2 + 1; q < 16; ++q) acb[q] += __shfl(cv[q], r2) * xr;
            }
            if (c < 16) {
#pragma unroll
                for (int r2 = 0; r2 < 16; ++r2)
                    Amat[(base + c) * PITCH + base + r2] = x[r2];   // T^T into diag block
            }
            if (c < 32) {
                int t2 = c & 15;
                float* zp = (c < 16) ? zv : zd;
                float a0 = 0.f;
#pragma unroll
                for (int a = 0; a < 16; ++a)
                    a0 += Amat[(base + a) * PITCH + base + t2] * zp[base + a];
                zp[base + t2] = a0;
            }
        } else if (p > 0 && R > 0) {
            // U_rest from prev panel: lower 8x8 tiles, rows/cols >= base+16
            int nt = R >> 3;
            int ntri = (nt * (nt + 1)) >> 1;
            for (int tau = tid - 64; tau < ntri; tau += 192) {
                float ft = sqrtf(8.f * (float)tau + 1.f);
                int tr = (int)((ft - 1.f) * 0.5f);
                while (((tr + 1) * (tr + 2)) / 2 <= tau) ++tr;
                while ((tr * (tr + 1)) / 2 > tau) --tr;
                int tc = tau - ((tr * (tr + 1)) >> 1);
                int ii = base + 16 + tr * 8, jj = base + 16 + tc * 8;
                float a2[8][8];
#pragma unroll
                for (int r2 = 0; r2 < 8; ++r2)
#pragma unroll
                    for (int c2 = 0; c2 < 8; ++c2) a2[r2][c2] = 0.f;
#pragma unroll
                for (int t = 0; t < 16; ++t) {
                    const float* wr = &Wb[t * PITCH];
                    float4 x0 = *(const float4*)&wr[ii];
                    float4 x1 = *(const float4*)&wr[ii + 4];
                    float4 y0 = *(const float4*)&wr[jj];
                    float4 y1 = *(const float4*)&wr[jj + 4];
                    float xa[8] = {x0.x,x0.y,x0.z,x0.w, x1.x,x1.y,x1.z,x1.w};
                    float yb[8] = {y0.x,y0.y,y0.z,y0.w, y1.x,y1.y,y1.z,y1.w};
#pragma unroll
                    for (int r2 = 0; r2 < 8; ++r2)
#pragma unroll
                        for (int c2 = 0; c2 < 8; ++c2) a2[r2][c2] += xa[r2] * yb[c2];
                }
#pragma unroll
                for (int r2 = 0; r2 < 8; ++r2) {
                    float* Ar2 = &Amat[(ii + r2) * PITCH + jj];
                    float4 u0 = *(float4*)&Ar2[0];
                    float4 u1 = *(float4*)&Ar2[4];
                    u0.x -= a2[r2][0]; u0.y -= a2[r2][1]; u0.z -= a2[r2][2]; u0.w -= a2[r2][3];
                    u1.x -= a2[r2][4]; u1.y -= a2[r2][5]; u1.z -= a2[r2][6]; u1.w -= a2[r2][7];
                    *(float4*)&Ar2[0] = u0;
                    *(float4*)&Ar2[4] = u1;
                }
            }
        }
        __syncthreads();                         // (c) T ready; Wb(prev) consumed
        if (R > 0 && tid < R) {
            int i = base + 16 + tid;
            const float* Ar = &Amat[i * PITCH + base];
            float4 q0 = *(const float4*)&Ar[0];
            float4 q1 = *(const float4*)&Ar[4];
            float4 q2 = *(const float4*)&Ar[8];
            float4 q3 = *(const float4*)&Ar[12];
            float rA[16] = {q0.x,q0.y,q0.z,q0.w, q1.x,q1.y,q1.z,q1.w,
                            q2.x,q2.y,q2.z,q2.w, q3.x,q3.y,q3.z,q3.w};
            float lo[16];
#pragma unroll
            for (int t = 0; t < 16; ++t) lo[t] = 0.f;
#pragma unroll
            for (int a = 0; a < 16; ++a) {
                float va = rA[a];
                const float* Trow = &Amat[(base + a) * PITCH + base];
                float4 t0 = *(const float4*)&Trow[0];
                float4 t1 = *(const float4*)&Trow[4];
                float4 t2 = *(const float4*)&Trow[8];
                float4 t3 = *(const float4*)&Trow[12];
                lo[0] += va * t0.x; lo[1] += va * t0.y; lo[2] += va * t0.z; lo[3] += va * t0.w;
                lo[4] += va * t1.x; lo[5] += va * t1.y; lo[6] += va * t1.z; lo[7] += va * t1.w;
                lo[8] += va * t2.x; lo[9] += va * t2.y; lo[10] += va * t2.z; lo[11] += va * t2.w;
                lo[12] += va * t3.x; lo[13] += va * t3.y; lo[14] += va * t3.z; lo[15] += va * t3.w;
            }
            float* Aw = &Amat[i * PITCH + base];
            *(float4*)&Aw[0]  = make_float4(lo[0], lo[1], lo[2], lo[3]);
            *(float4*)&Aw[4]  = make_float4(lo[4], lo[5], lo[6], lo[7]);
            *(float4*)&Aw[8]  = make_float4(lo[8], lo[9], lo[10], lo[11]);
            *(float4*)&Aw[12] = make_float4(lo[12], lo[13], lo[14], lo[15]);
#pragma unroll
            for (int t = 0; t < 16; ++t) Wb[t * PITCH + i] = lo[t];
        }
    }
    // ---- phase 3b: X = L^{-1} via 7 block-sweeps; 4x4 register tiles
    for (int s2 = 1; s2 <= 7; ++s2) {
        __syncthreads();
        int npair = 8 - s2;
        int jobs = npair * 16;
        int len = 16 * s2;
        for (int t = tid; t < jobs; t += 256) {
            int pr = t >> 4;
            int ta = (t >> 2) & 3, tb = t & 3;
            int i = pr + s2, J = pr;
            const float* u0 = &Amat[(16 * i + ta * 4) * PITCH + 16 * J];
            const float* w0 = &Amat[(16 * J + tb * 4) * PITCH + 16 * J];
            float a4[4][4];
#pragma unroll
            for (int r2 = 0; r2 < 4; ++r2)
#pragma unroll
                for (int c2 = 0; c2 < 4; ++c2) a4[r2][c2] = 0.f;
            for (int k = 0; k < len; k += 4) {
                float4 ur[4], wr4[4];
#pragma unroll
                for (int r2 = 0; r2 < 4; ++r2) ur[r2] = *(const float4*)&u0[r2 * PITCH + k];
#pragma unroll
                for (int c2 = 0; c2 < 4; ++c2) wr4[c2] = *(const float4*)&w0[c2 * PITCH + k];
#pragma unroll
                for (int r2 = 0; r2 < 4; ++r2)
#pragma unroll
                    for (int c2 = 0; c2 < 4; ++c2)
                        a4[r2][c2] += ur[r2].x * wr4[c2].x + ur[r2].y * wr4[c2].y
                                    + ur[r2].z * wr4[c2].z + ur[r2].w * wr4[c2].w;
            }
#pragma unroll
            for (int r2 = 0; r2 < 4; ++r2)
#pragma unroll
                for (int c2 = 0; c2 < 4; ++c2)
                    Sbuf[pr * 256 + (ta * 4 + r2) * 16 + tb * 4 + c2] = a4[r2][c2];
        }
        __syncthreads();
        for (int idx = tid; idx < npair * 256; idx += 256) {
            int pr = idx >> 8;
            int J = pr, i = pr + s2;
            int cc = (idx >> 4) & 15, bb = idx & 15;
            float a0 = 0.f;
#pragma unroll
            for (int a = 0; a < 16; ++a)
                a0 += Amat[(16 * i + a) * PITCH + 16 * i + cc] * Sbuf[pr * 256 + a * 16 + bb];
            Amat[(16 * J + bb) * PITCH + 16 * i + cc] = -a0;
        }
    }
    __syncthreads();
    // ---- phase 4: trinv, qv, qd (one batched reduction)
    float v3[3] = {0.f, 0.f, 0.f};
    {
        int i = tid & 127, h = tid >> 7;
        int c0 = (i >> 4) << 4;
        int half = (128 - c0) >> 1;
        const float* Ar = &Amat[i * PITCH + c0 + h * half];
        for (int k2 = 0; k2 < half; k2 += 4) {
            float4 a = *(const float4*)&Ar[k2];
            v3[0] += a.x * a.x + a.y * a.y + a.z * a.z + a.w * a.w;
        }
    }
    if (tid < 128) {
        float a = zv[tid];  v3[1] = a * a;
        float d22 = zd[tid]; v3[2] = d22 * d22;
    }
    bsumN<3>(v3, red);
    if (tid == 0) {
        float n = 1.f + nv;
        float Aterm = trP - vsv / n;              // tr(Sq^{-1} Sp)
        float Bt = v3[0] + v3[1];                 // tr(Sp^{-1} Sq)
        float mq = dds - vds * vds / n;           // delta^T Sq^{-1} delta
        out[bid] = 0.25f * (Aterm + Bt - 256.f + mq + v3[2]);
    }
}

// ---------------------------------------------------------------- launch
extern "C" void kernel_launch(void* const* d_in, const int* in_sizes, int n_in,
                              void* d_out, int out_size, void* d_ws, size_t ws_size,
                              hipStream_t stream) {
    const float* wfm = (const float*)d_in[0];
    const float* wfd = (const float*)d_in[1];
    const float* sfm = (const float*)d_in[2];
    const float* sfd = (const float*)d_in[3];
    const float* W1 = (const float*)d_in[4];
    const float* B1 = (const float*)d_in[5];
    const float* W2 = (const float*)d_in[6];
    const float* B2 = (const float*)d_in[7];
    const float* W3 = (const float*)d_in[8];
    const float* B3 = (const float*)d_in[9];
    const float* W4 = (const float*)d_in[10];
    const float* B4 = (const float*)d_in[11];
    const float* lm = (const float*)d_in[12];
    const float* ldv = (const float*)d_in[13];
    float* out = (float*)d_out;
    float* ws = (float*)d_ws;

    float* wm = ws;                           // 262144
    float* wv = ws + 262144;                  // 262144
    float* sm = ws + 524288;                  // 1024
    float* sv = ws + 525312;                  // 1024
    unsigned short* wvTg = (unsigned short*)(ws + 731392);  // 262144 bf16

    constexpr int SH_FLOATS = 19800;
    constexpr size_t SH_BYTES = SH_FLOATS * sizeof(float);   // 79200 B -> 2 blocks/CU
    (void)hipFuncSetAttribute((const void*)k4_fused,
                              hipFuncAttributeMaxDynamicSharedMemorySize,
                              (int)SH_BYTES);

    k1_gemm<<<dim3(129, 2), 256, 0, stream>>>(wfm, wfd, sfm, sfd,
                                              W1, B1, W2, B2, W3, B3, W4, B4,
                                              wm, wv, sm, sv, wvTg);
    k4_fused<<<512, 256, SH_BYTES, stream>>>(wm, wv, wvTg, sm, sv, lm, ldv, out);
}